// Round 21
// baseline (84.543 us; speedup 1.0000x reference)
//
#include <hip/hip_runtime.h>

#define E_TOT 320000
#define NN    10000
#define DN    128
#define DE    32
#define DH    192
#define DO    128
#define EB    64
#define SHS   196   // s_h row stride in ushorts (392 B)

typedef __attribute__((ext_vector_type(8))) short bf16x8;
typedef __attribute__((ext_vector_type(4))) float f32x4;

#define E_FRAGS  (12*64)      // W1_edge^T A-frags (edge GEMM1)
#define W2_FRAGS (6*8*64)     // W2 B-frags (node_out)
#define FRAGS_TOT (E_FRAGS + W2_FRAGS)
#define ZH (NN * DH / 4)      // Hbar zero items (float4)
#define PREP_ITEMS (FRAGS_TOT + ZH + E_TOT)
#define NPROJ (((NN + 63) / 64) * 2)              // 314 node_proj blocks
__device__ __align__(16) unsigned short g_e [E_FRAGS * 8];
__device__ __align__(16) unsigned short g_p2[W2_FRAGS * 8];

__device__ __forceinline__ unsigned short f2bf(float f) {
    union { float f; unsigned u; } v; v.f = f;
    return (unsigned short)((v.u + 0x7FFFu + ((v.u >> 16) & 1u)) >> 16);
}
__device__ __forceinline__ float bflo(unsigned u) {
    union { unsigned v; float f; } t; t.v = u << 16; return t.f;
}
__device__ __forceinline__ float bfhi(unsigned u) {
    union { unsigned v; float f; } t; t.v = u & 0xFFFF0000u; return t.f;
}
__device__ __forceinline__ float bf2f(unsigned short s) {
    union { unsigned v; float f; } t; t.v = (unsigned)s << 16; return t.f;
}
__device__ __forceinline__ float tanh_fast(float x) {
    float ex = __expf(x + x);
    return 1.0f - 2.0f * __builtin_amdgcn_rcpf(ex + 1.0f);
}
__device__ __forceinline__ unsigned cvt_pk_bf16(float lo, float hi) {
    unsigned r;
    asm("v_cvt_pk_bf16_f32 %0, %1, %2" : "=v"(r) : "v"(lo), "v"(hi));
    return r;
}

// ---------------------------------------------------------------------------
// prep_proj (= R19/R20 verbatim)
// ---------------------------------------------------------------------------
__global__ __launch_bounds__(256) void prep_proj(
    const float* __restrict__ n_embed, const float* __restrict__ W1,
    const float* __restrict__ W2, const float* __restrict__ b1,
    const int* __restrict__ senders,
    unsigned short* __restrict__ P, float* __restrict__ Hbar,
    int* __restrict__ row_start)
{
    __shared__ __align__(16) unsigned short s_a[64][136];
    const int tid = threadIdx.x;

    if (blockIdx.x >= NPROJ) {
        int f = (blockIdx.x - NPROJ) * 256 + tid;
        unsigned short tmp[8];
        if (f < E_FRAGS) {
            int mt = f >> 6, lane = f & 63;
            int k0 = ((lane >> 4) << 3);
            int hid = mt * 16 + (lane & 15);
            #pragma unroll
            for (int i = 0; i < 8; ++i) tmp[i] = f2bf(W1[(256 + k0 + i) * DH + hid]);
            *(uint4*)(g_e + (size_t)f * 8) = *(const uint4*)tmp;
        } else if (f < FRAGS_TOT) {
            int f3 = f - E_FRAGS;
            int kk = f3 / (8 * 64), nt = (f3 >> 6) % 8, lane = f3 & 63;
            int r0 = kk * 32 + ((lane >> 4) << 3);
            int c  = nt * 16 + (lane & 15);
            #pragma unroll
            for (int i = 0; i < 8; ++i) tmp[i] = f2bf(W2[(r0 + i) * DO + c]);
            *(uint4*)(g_p2 + (size_t)f3 * 8) = *(const uint4*)tmp;
        } else if (f < FRAGS_TOT + ZH) {
            ((float4*)Hbar)[f - FRAGS_TOT] = make_float4(0.f, 0.f, 0.f, 0.f);
        } else if (f < PREP_ITEMS) {
            int e = f - FRAGS_TOT - ZH;
            int s_cur  = senders[e];
            int s_prev = (e == 0) ? -1 : senders[e - 1];
            if (s_prev != s_cur)
                for (int n = s_prev + 1; n <= s_cur; ++n) row_start[n] = e;
            if (e == E_TOT - 1)
                for (int n = s_cur + 1; n <= NN; ++n) row_start[n] = E_TOT;
        }
        return;
    }

    const int half = blockIdx.x & 1;
    const int n0   = (blockIdx.x >> 1) * 64;

    #pragma unroll
    for (int it = 0; it < 8; ++it) {
        int idx = tid + it * 256;
        int row = idx >> 5, c = idx & 31;
        float4 v = make_float4(0.f, 0.f, 0.f, 0.f);
        if (n0 + row < NN) v = ((const float4*)(n_embed + (size_t)(n0 + row) * DN))[c];
        unsigned t0 = cvt_pk_bf16(v.x, v.y), t1 = cvt_pk_bf16(v.z, v.w);
        *(uint2*)&s_a[row][c * 4] = make_uint2(t0, t1);
    }
    __syncthreads();

    const int lane = tid & 63, w = tid >> 6;
    const int arow = lane & 15, akb = (lane >> 4) * 8, rbase = (lane >> 4) * 4;

    f32x4 acc[4][3];
    #pragma unroll
    for (int mt = 0; mt < 4; ++mt)
        #pragma unroll
        for (int j = 0; j < 3; ++j) acc[mt][j] = (f32x4){0.f, 0.f, 0.f, 0.f};

    for (int kk = 0; kk < 4; ++kk) {
        bf16x8 a[4];
        union { bf16x8 v; unsigned short t[8]; } b[3];
        #pragma unroll
        for (int mt = 0; mt < 4; ++mt)
            a[mt] = *(const bf16x8*)&s_a[mt * 16 + arow][kk * 32 + akb];
        #pragma unroll
        for (int j = 0; j < 3; ++j) {
            const int r0 = (kk + 4 * half) * 32 + akb;
            const int c  = (3 * w + j) * 16 + arow;
            #pragma unroll
            for (int i = 0; i < 8; ++i) b[j].t[i] = f2bf(W1[(size_t)(r0 + i) * DH + c]);
        }
        #pragma unroll
        for (int mt = 0; mt < 4; ++mt)
            #pragma unroll
            for (int j = 0; j < 3; ++j)
                acc[mt][j] = __builtin_amdgcn_mfma_f32_16x16x32_bf16(a[mt], b[j].v, acc[mt][j], 0, 0, 0);
    }

    unsigned short* Pout = P + (size_t)half * NN * DH;
    float bj[3];
    #pragma unroll
    for (int j = 0; j < 3; ++j) bj[j] = (half == 0) ? b1[48 * w + 16 * j + arow] : 0.f;
    const int gq = arow >> 2, ii = arow & 3;
    #pragma unroll
    for (int mt = 0; mt < 4; ++mt)
        #pragma unroll
        for (int j = 0; j < 3; ++j)
            #pragma unroll
            for (int r = 0; r < 4; ++r) {
                int row = n0 + mt * 16 + rbase + r;
                if (row < NN)
                    Pout[((size_t)row * 4 + gq) * 48 + (3 * w + j) * 4 + ii] =
                        f2bf(acc[mt][j][r] + bj[j]);
            }
}

// ---------------------------------------------------------------------------
// edge kernel, TWO tiles per block with cross-tile overlap:
//   gather(A) -> phase1(A) -> barrier -> issue gather(B) -> reduce(A)
//   -> barrier -> phase1(B) -> barrier -> reduce(B).
//   Tile B's 13 global loads hide under reduce(A)'s LDS walk.
// ---------------------------------------------------------------------------
struct Gather {
    uint4 psq[6], prq[6];
    union { bf16x8 v; unsigned u[4]; } bfr;
};

__device__ __forceinline__ void issue_gather(
    int e0, int lane, int w, int arow, int g,
    const float* __restrict__ e_embed,
    const int* __restrict__ senders, const int* __restrict__ receivers,
    const unsigned short* __restrict__ Ps, const unsigned short* __restrict__ Pr,
    Gather& gt)
{
    const int myedge = e0 + w * 16 + arow;
    const int sN = senders[myedge], rN = receivers[myedge];
    const unsigned short* psbase = Ps + ((size_t)sN * 4 + g) * 48;
    const unsigned short* prbase = Pr + ((size_t)rN * 4 + g) * 48;
    #pragma unroll
    for (int j = 0; j < 6; ++j) {
        gt.psq[j] = *(const uint4*)(psbase + j * 8);
        gt.prq[j] = *(const uint4*)(prbase + j * 8);
    }
    const float* erow = e_embed + (size_t)myedge * DE + g * 8;
    float4 ev0 = *(const float4*)erow;
    float4 ev1 = *(const float4*)(erow + 4);
    gt.bfr.u[0] = cvt_pk_bf16(ev0.x, ev0.y);
    gt.bfr.u[1] = cvt_pk_bf16(ev0.z, ev0.w);
    gt.bfr.u[2] = cvt_pk_bf16(ev1.x, ev1.y);
    gt.bfr.u[3] = cvt_pk_bf16(ev1.z, ev1.w);
}

__device__ __forceinline__ void phase1_tile(
    const Gather& gt, int lane, int w, int arow, int g,
    unsigned short (*s_h)[SHS])
{
    #pragma unroll
    for (int mt = 0; mt < 12; ++mt) {
        unsigned px, py, qx, qy;
        if ((mt & 1) == 0) {
            px = gt.psq[mt >> 1].x; py = gt.psq[mt >> 1].y;
            qx = gt.prq[mt >> 1].x; qy = gt.prq[mt >> 1].y;
        } else {
            px = gt.psq[mt >> 1].z; py = gt.psq[mt >> 1].w;
            qx = gt.prq[mt >> 1].z; qy = gt.prq[mt >> 1].w;
        }
        f32x4 cinit;
        cinit[0] = bflo(px) + bflo(qx);
        cinit[1] = bfhi(px) + bfhi(qx);
        cinit[2] = bflo(py) + bflo(qy);
        cinit[3] = bfhi(py) + bfhi(qy);
        bf16x8 af = *(const bf16x8*)(g_e + ((size_t)mt * 64 + lane) * 8);
        f32x4 acc = __builtin_amdgcn_mfma_f32_16x16x32_bf16(af, gt.bfr.v, cinit, 0, 0, 0);
        float t0 = tanh_fast(acc[0]);
        float t1 = tanh_fast(acc[1]);
        float t2 = tanh_fast(acc[2]);
        float t3 = tanh_fast(acc[3]);
        *(uint2*)&s_h[w * 16 + arow][mt * 16 + g * 4] =
            make_uint2(cvt_pk_bf16(t0, t1), cvt_pk_bf16(t2, t3));
    }
}

__device__ __forceinline__ void reduce_tile(
    int tid, const int* s_send, unsigned short (*s_h)[SHS],
    float* __restrict__ Hbar)
{
    if (tid < DH) {
        const int c = tid;
        float sum = 0.f;
        int cur = s_send[0];
        #pragma unroll 8
        for (int e = 0; e < EB; ++e) {
            sum += bf2f(s_h[e][c]);
            int nxt = (e + 1 < EB) ? s_send[e + 1] : -1;
            if (nxt != cur) {
                atomicAdd(&Hbar[(size_t)cur * DH + c], sum);
                sum = 0.f;
                cur = nxt;
            }
        }
    }
}

__global__ __launch_bounds__(256) void edge_reduce(
    const float* __restrict__ e_embed,
    const int* __restrict__ senders, const int* __restrict__ receivers,
    const unsigned short* __restrict__ Ps, const unsigned short* __restrict__ Pr,
    float* __restrict__ Hbar)
{
    __shared__ __align__(16) unsigned short s_h[EB][SHS];  // 25088 B
    __shared__ int s_send[2][EB];

    const int tid = threadIdx.x;
    // bijective XCD swizzle (2500 % 8 != 0 -> m204 formula)
    const int nwg = gridDim.x, q = nwg >> 3, r = nwg & 7;
    const int xcd = blockIdx.x & 7, loc = blockIdx.x >> 3;
    const int wg  = (xcd < r) ? (xcd * (q + 1) + loc)
                              : (r * (q + 1) + (xcd - r) * q + loc);
    const int e0  = wg * 2 * EB;   // two consecutive tiles
    const int lane = tid & 63, w = tid >> 6;
    const int arow = lane & 15, g = lane >> 4;

    // ---- tile A: gather + staging ----
    Gather ga;
    issue_gather(e0, lane, w, arow, g, e_embed, senders, receivers, Ps, Pr, ga);
    if (tid < EB) {
        s_send[0][tid] = senders[e0 + tid];
        s_send[1][tid] = senders[e0 + EB + tid];
    }

    // ---- phase 1(A) -> s_h ----
    phase1_tile(ga, lane, w, arow, g, s_h);
    __syncthreads();

    // ---- issue gather(B) BEFORE reduce(A): loads fly under the LDS walk ----
    Gather gb;
    issue_gather(e0 + EB, lane, w, arow, g, e_embed, senders, receivers, Ps, Pr, gb);

    // ---- reduce(A): LDS + atomics only ----
    reduce_tile(tid, s_send[0], s_h, Hbar);
    __syncthreads();   // all reads of s_h(A) done

    // ---- phase 1(B) -> s_h ----
    phase1_tile(gb, lane, w, arow, g, s_h);
    __syncthreads();

    // ---- reduce(B) ----
    reduce_tile(tid, s_send[1], s_h, Hbar);
}

// ---------------------------------------------------------------------------
// node_out v3 (= R19/R20 verbatim)
// ---------------------------------------------------------------------------
__global__ __launch_bounds__(256) void node_out(
    const float* __restrict__ Hbar, const int* __restrict__ row_start,
    const float* __restrict__ b2, float* __restrict__ out)
{
    const int tid  = threadIdx.x;
    const int lane = tid & 63, w = tid >> 6;
    const int n0   = (blockIdx.x * 4 + w) * 16;
    if (n0 >= NN) return;
    const int arow = lane & 15, akb = (lane >> 4) * 8, rbase = (lane >> 4) * 4;

    const int myrow = (n0 + arow < NN) ? (n0 + arow) : (NN - 1);
    const int cnt = row_start[myrow + 1] - row_start[myrow];
    const float ic = (cnt > 0) ? 1.0f / (float)cnt : 0.0f;

    const float* hrow = Hbar + (size_t)myrow * DH;
    union { bf16x8 v; unsigned u[4]; } a[6];
    #pragma unroll
    for (int kk = 0; kk < 6; ++kk) {
        float4 v0 = *(const float4*)(hrow + kk * 32 + akb);
        float4 v1 = *(const float4*)(hrow + kk * 32 + akb + 4);
        a[kk].u[0] = cvt_pk_bf16(v0.x * ic, v0.y * ic);
        a[kk].u[1] = cvt_pk_bf16(v0.z * ic, v0.w * ic);
        a[kk].u[2] = cvt_pk_bf16(v1.x * ic, v1.y * ic);
        a[kk].u[3] = cvt_pk_bf16(v1.z * ic, v1.w * ic);
    }

    f32x4 acc[8];
    #pragma unroll
    for (int j = 0; j < 8; ++j) acc[j] = (f32x4){0.f, 0.f, 0.f, 0.f};

    #pragma unroll
    for (int kk = 0; kk < 6; ++kk)
        #pragma unroll
        for (int j = 0; j < 8; ++j) {
            bf16x8 b = *(const bf16x8*)(g_p2 + (((size_t)kk * 8 + j) * 64 + lane) * 8);
            acc[j] = __builtin_amdgcn_mfma_f32_16x16x32_bf16(a[kk].v, b, acc[j], 0, 0, 0);
        }

    #pragma unroll
    for (int j = 0; j < 8; ++j) {
        const float bd = b2[j * 16 + arow];
        #pragma unroll
        for (int r = 0; r < 4; ++r) {
            int row = n0 + rbase + r;
            if (row < NN)
                out[(size_t)row * DO + j * 16 + arow] = acc[j][r] + bd;
        }
    }
}

extern "C" void kernel_launch(void* const* d_in, const int* in_sizes, int n_in,
                              void* d_out, int out_size, void* d_ws, size_t ws_size,
                              hipStream_t stream)
{
    const float* n_embed   = (const float*)d_in[0];
    const float* e_embed   = (const float*)d_in[1];
    const int*   senders   = (const int*)d_in[2];
    const int*   receivers = (const int*)d_in[3];
    const float* W1        = (const float*)d_in[4];
    const float* b1        = (const float*)d_in[5];
    const float* W2        = (const float*)d_in[6];
    const float* b2        = (const float*)d_in[7];
    float* out = (float*)d_out;

    unsigned short* Ps   = (unsigned short*)d_ws;             // [NN][192] bf16 (lane-packed)
    unsigned short* Pr   = Ps + (size_t)NN * DH;              // [NN][192] bf16 (lane-packed)
    float*          Hbar = (float*)(Pr + (size_t)NN * DH);    // [NN][192] f32
    int*            row_start = (int*)(Hbar + (size_t)NN * DH);  // [NN+1]

    const int prep_blocks = (PREP_ITEMS + 255) / 256;         // 3140
    prep_proj<<<NPROJ + prep_blocks, 256, 0, stream>>>(
        n_embed, W1, W2, b1, senders, Ps, Hbar, row_start);
    edge_reduce<<<E_TOT / (2 * EB), 256, 0, stream>>>(
        e_embed, senders, receivers, Ps, Pr, Hbar);
    node_out<<<(NN + 63) / 64, 256, 0, stream>>>(Hbar, row_start, b2, out);
}

// Round 22
// 75.524 us; speedup vs baseline: 1.1194x; 1.1194x over previous
//
#include <hip/hip_runtime.h>

#define E_TOT 320000
#define NN    10000
#define DN    128
#define DE    32
#define DH    192
#define DO    128
#define EB    64
#define SHS   196   // s_h row stride in ushorts (392 B)

typedef __attribute__((ext_vector_type(8))) short bf16x8;
typedef __attribute__((ext_vector_type(4))) float f32x4;

// packed weight tables (rewritten every launch); W1-node frags are read
// directly from W1 inside prep_proj (no cross-block dep)
#define E_FRAGS  (12*64)      // W1_edge^T A-frags (edge GEMM1)
#define W2_FRAGS (6*8*64)     // W2 B-frags (node_out)
#define FRAGS_TOT (E_FRAGS + W2_FRAGS)
#define ZH (NN * DH / 4)      // Hbar zero items (float4)
#define PREP_ITEMS (FRAGS_TOT + ZH + E_TOT)
#define NPROJ (((NN + 63) / 64) * 2)              // 314 node_proj blocks
__device__ __align__(16) unsigned short g_e [E_FRAGS * 8];
__device__ __align__(16) unsigned short g_p2[W2_FRAGS * 8];

__device__ __forceinline__ unsigned short f2bf(float f) {
    union { float f; unsigned u; } v; v.f = f;
    return (unsigned short)((v.u + 0x7FFFu + ((v.u >> 16) & 1u)) >> 16);
}
__device__ __forceinline__ float bflo(unsigned u) {
    union { unsigned v; float f; } t; t.v = u << 16; return t.f;
}
__device__ __forceinline__ float bfhi(unsigned u) {
    union { unsigned v; float f; } t; t.v = u & 0xFFFF0000u; return t.f;
}
__device__ __forceinline__ float bf2f(unsigned short s) {
    union { unsigned v; float f; } t; t.v = (unsigned)s << 16; return t.f;
}
__device__ __forceinline__ float tanh_fast(float x) {
    float ex = __expf(x + x);
    return 1.0f - 2.0f * __builtin_amdgcn_rcpf(ex + 1.0f);
}
__device__ __forceinline__ unsigned cvt_pk_bf16(float lo, float hi) {
    unsigned r;
    asm("v_cvt_pk_bf16_f32 %0, %1, %2" : "=v"(r) : "v"(lo), "v"(hi));
    return r;
}

// ---------------------------------------------------------------------------
// prep_proj: blocks [0,NPROJ) = node projections (direct W1 reads);
//            blocks [NPROJ,..) = pack g_e/g_p2 + zero Hbar + row_start.
// No cross-block dependencies inside this dispatch.
// ---------------------------------------------------------------------------
__global__ __launch_bounds__(256) void prep_proj(
    const float* __restrict__ n_embed, const float* __restrict__ W1,
    const float* __restrict__ W2, const float* __restrict__ b1,
    const int* __restrict__ senders,
    unsigned short* __restrict__ P, float* __restrict__ Hbar,
    int* __restrict__ row_start)
{
    __shared__ __align__(16) unsigned short s_a[64][136];
    const int tid = threadIdx.x;

    if (blockIdx.x >= NPROJ) {
        // ---- prep items ----
        int f = (blockIdx.x - NPROJ) * 256 + tid;
        unsigned short tmp[8];
        if (f < E_FRAGS) {                        // W1_edge^T A-frags
            int mt = f >> 6, lane = f & 63;
            int k0 = ((lane >> 4) << 3);
            int hid = mt * 16 + (lane & 15);
            #pragma unroll
            for (int i = 0; i < 8; ++i) tmp[i] = f2bf(W1[(256 + k0 + i) * DH + hid]);
            *(uint4*)(g_e + (size_t)f * 8) = *(const uint4*)tmp;
        } else if (f < FRAGS_TOT) {               // W2 B-frags
            int f3 = f - E_FRAGS;
            int kk = f3 / (8 * 64), nt = (f3 >> 6) % 8, lane = f3 & 63;
            int r0 = kk * 32 + ((lane >> 4) << 3);
            int c  = nt * 16 + (lane & 15);
            #pragma unroll
            for (int i = 0; i < 8; ++i) tmp[i] = f2bf(W2[(r0 + i) * DO + c]);
            *(uint4*)(g_p2 + (size_t)f3 * 8) = *(const uint4*)tmp;
        } else if (f < FRAGS_TOT + ZH) {          // zero Hbar (float4)
            ((float4*)Hbar)[f - FRAGS_TOT] = make_float4(0.f, 0.f, 0.f, 0.f);
        } else if (f < PREP_ITEMS) {              // row_start builder
            int e = f - FRAGS_TOT - ZH;
            int s_cur  = senders[e];
            int s_prev = (e == 0) ? -1 : senders[e - 1];
            if (s_prev != s_cur)
                for (int n = s_prev + 1; n <= s_cur; ++n) row_start[n] = e;
            if (e == E_TOT - 1)
                for (int n = s_cur + 1; n <= NN; ++n) row_start[n] = E_TOT;
        }
        return;
    }

    // ---- node projections: P'[n][g][mt][i] lane-contiguous layout ----
    const int half = blockIdx.x & 1;
    const int n0   = (blockIdx.x >> 1) * 64;

    #pragma unroll
    for (int it = 0; it < 8; ++it) {
        int idx = tid + it * 256;
        int row = idx >> 5, c = idx & 31;
        float4 v = make_float4(0.f, 0.f, 0.f, 0.f);
        if (n0 + row < NN) v = ((const float4*)(n_embed + (size_t)(n0 + row) * DN))[c];
        unsigned t0 = cvt_pk_bf16(v.x, v.y), t1 = cvt_pk_bf16(v.z, v.w);
        *(uint2*)&s_a[row][c * 4] = make_uint2(t0, t1);
    }
    __syncthreads();

    const int lane = tid & 63, w = tid >> 6;
    const int arow = lane & 15, akb = (lane >> 4) * 8, rbase = (lane >> 4) * 4;

    f32x4 acc[4][3];
    #pragma unroll
    for (int mt = 0; mt < 4; ++mt)
        #pragma unroll
        for (int j = 0; j < 3; ++j) acc[mt][j] = (f32x4){0.f, 0.f, 0.f, 0.f};

    for (int kk = 0; kk < 4; ++kk) {
        bf16x8 a[4];
        union { bf16x8 v; unsigned short t[8]; } b[3];
        #pragma unroll
        for (int mt = 0; mt < 4; ++mt)
            a[mt] = *(const bf16x8*)&s_a[mt * 16 + arow][kk * 32 + akb];
        // direct W1 B-frags: row r0+i = (kk+4*half)*32 + (lane>>4)*8 + i,
        // col = (3w+j)*16 + arow  (same values/rounding as the packed table)
        #pragma unroll
        for (int j = 0; j < 3; ++j) {
            const int r0 = (kk + 4 * half) * 32 + akb;
            const int c  = (3 * w + j) * 16 + arow;
            #pragma unroll
            for (int i = 0; i < 8; ++i) b[j].t[i] = f2bf(W1[(size_t)(r0 + i) * DH + c]);
        }
        #pragma unroll
        for (int mt = 0; mt < 4; ++mt)
            #pragma unroll
            for (int j = 0; j < 3; ++j)
                acc[mt][j] = __builtin_amdgcn_mfma_f32_16x16x32_bf16(a[mt], b[j].v, acc[mt][j], 0, 0, 0);
    }

    unsigned short* Pout = P + (size_t)half * NN * DH;
    float bj[3];
    #pragma unroll
    for (int j = 0; j < 3; ++j) bj[j] = (half == 0) ? b1[48 * w + 16 * j + arow] : 0.f;
    const int gq = arow >> 2, ii = arow & 3;
    #pragma unroll
    for (int mt = 0; mt < 4; ++mt)
        #pragma unroll
        for (int j = 0; j < 3; ++j)
            #pragma unroll
            for (int r = 0; r < 4; ++r) {
                int row = n0 + mt * 16 + rbase + r;
                if (row < NN)
                    Pout[((size_t)row * 4 + gq) * 48 + (3 * w + j) * 4 + ii] =
                        f2bf(acc[mt][j][r] + bj[j]);
            }
}

// ---------------------------------------------------------------------------
// edge kernel: gather + GEMM1^T (P-add folded into MFMA C-input) + tanh ->
// s_h; one barrier; per-column segment reduce -> RAW sums into Hbar.
// ---------------------------------------------------------------------------
__global__ __launch_bounds__(256) void edge_reduce(
    const float* __restrict__ e_embed,
    const int* __restrict__ senders, const int* __restrict__ receivers,
    const unsigned short* __restrict__ Ps, const unsigned short* __restrict__ Pr,
    float* __restrict__ Hbar)
{
    __shared__ __align__(16) unsigned short s_h[EB][SHS];  // 25088 B
    __shared__ int s_send[EB];

    const int tid  = threadIdx.x;
    const int nb8  = gridDim.x >> 3;                       // 625
    const int e0   = (((blockIdx.x & 7) * nb8) + (blockIdx.x >> 3)) * EB;  // XCD swizzle
    const int lane = tid & 63, w = tid >> 6;
    const int arow = lane & 15, g = lane >> 4;

    // ---- phase 0: per-lane loads (wide, contiguous per lane) ----
    const int myedge = e0 + w * 16 + arow;
    const int sN = senders[myedge], rN = receivers[myedge];
    const unsigned short* psbase = Ps + ((size_t)sN * 4 + g) * 48;
    const unsigned short* prbase = Pr + ((size_t)rN * 4 + g) * 48;
    uint4 psq[6], prq[6];
    #pragma unroll
    for (int j = 0; j < 6; ++j) {
        psq[j] = *(const uint4*)(psbase + j * 8);
        prq[j] = *(const uint4*)(prbase + j * 8);
    }
    union { bf16x8 v; unsigned u[4]; } bfr;
    {
        const float* erow = e_embed + (size_t)myedge * DE + g * 8;
        float4 ev0 = *(const float4*)erow;
        float4 ev1 = *(const float4*)(erow + 4);
        bfr.u[0] = cvt_pk_bf16(ev0.x, ev0.y);
        bfr.u[1] = cvt_pk_bf16(ev0.z, ev0.w);
        bfr.u[2] = cvt_pk_bf16(ev1.x, ev1.y);
        bfr.u[3] = cvt_pk_bf16(ev1.z, ev1.w);
    }
    if (tid < EB) s_send[tid] = senders[e0 + tid];

    // ---- phase 1: GEMM1^T, C-input = Ps+Pr; tanh -> s_h[edge][hid] ----
    #pragma unroll
    for (int mt = 0; mt < 12; ++mt) {
        unsigned px, py, qx, qy;
        if ((mt & 1) == 0) {
            px = psq[mt >> 1].x; py = psq[mt >> 1].y;
            qx = prq[mt >> 1].x; qy = prq[mt >> 1].y;
        } else {
            px = psq[mt >> 1].z; py = psq[mt >> 1].w;
            qx = prq[mt >> 1].z; qy = prq[mt >> 1].w;
        }
        f32x4 cinit;
        cinit[0] = bflo(px) + bflo(qx);
        cinit[1] = bfhi(px) + bfhi(qx);
        cinit[2] = bflo(py) + bflo(qy);
        cinit[3] = bfhi(py) + bfhi(qy);
        bf16x8 af = *(const bf16x8*)(g_e + ((size_t)mt * 64 + lane) * 8);
        f32x4 acc = __builtin_amdgcn_mfma_f32_16x16x32_bf16(af, bfr.v, cinit, 0, 0, 0);
        float t0 = tanh_fast(acc[0]);
        float t1 = tanh_fast(acc[1]);
        float t2 = tanh_fast(acc[2]);
        float t3 = tanh_fast(acc[3]);
        *(uint2*)&s_h[w * 16 + arow][mt * 16 + g * 4] =
            make_uint2(cvt_pk_bf16(t0, t1), cvt_pk_bf16(t2, t3));
    }
    __syncthreads();

    // ---- phase 2: per-column segment reduce of h (sorted senders) -> Hbar ----
    if (tid < DH) {
        const int c = tid;
        float sum = 0.f;
        int cur = s_send[0];
        #pragma unroll 8
        for (int e = 0; e < EB; ++e) {
            sum += bf2f(s_h[e][c]);
            int nxt = (e + 1 < EB) ? s_send[e + 1] : -1;
            if (nxt != cur) {
                atomicAdd(&Hbar[(size_t)cur * DH + c], sum);
                sum = 0.f;
                cur = nxt;
            }
        }
    }
}

// ---------------------------------------------------------------------------
// node_out v3: one independent wave per 16 rows; counts from row_start.
// ---------------------------------------------------------------------------
__global__ __launch_bounds__(256) void node_out(
    const float* __restrict__ Hbar, const int* __restrict__ row_start,
    const float* __restrict__ b2, float* __restrict__ out)
{
    const int tid  = threadIdx.x;
    const int lane = tid & 63, w = tid >> 6;
    const int n0   = (blockIdx.x * 4 + w) * 16;
    if (n0 >= NN) return;
    const int arow = lane & 15, akb = (lane >> 4) * 8, rbase = (lane >> 4) * 4;

    const int myrow = (n0 + arow < NN) ? (n0 + arow) : (NN - 1);
    const int cnt = row_start[myrow + 1] - row_start[myrow];
    const float ic = (cnt > 0) ? 1.0f / (float)cnt : 0.0f;

    const float* hrow = Hbar + (size_t)myrow * DH;
    union { bf16x8 v; unsigned u[4]; } a[6];
    #pragma unroll
    for (int kk = 0; kk < 6; ++kk) {
        float4 v0 = *(const float4*)(hrow + kk * 32 + akb);
        float4 v1 = *(const float4*)(hrow + kk * 32 + akb + 4);
        a[kk].u[0] = cvt_pk_bf16(v0.x * ic, v0.y * ic);
        a[kk].u[1] = cvt_pk_bf16(v0.z * ic, v0.w * ic);
        a[kk].u[2] = cvt_pk_bf16(v1.x * ic, v1.y * ic);
        a[kk].u[3] = cvt_pk_bf16(v1.z * ic, v1.w * ic);
    }

    f32x4 acc[8];
    #pragma unroll
    for (int j = 0; j < 8; ++j) acc[j] = (f32x4){0.f, 0.f, 0.f, 0.f};

    #pragma unroll
    for (int kk = 0; kk < 6; ++kk)
        #pragma unroll
        for (int j = 0; j < 8; ++j) {
            bf16x8 b = *(const bf16x8*)(g_p2 + (((size_t)kk * 8 + j) * 64 + lane) * 8);
            acc[j] = __builtin_amdgcn_mfma_f32_16x16x32_bf16(a[kk].v, b, acc[j], 0, 0, 0);
        }

    #pragma unroll
    for (int j = 0; j < 8; ++j) {
        const float bd = b2[j * 16 + arow];
        #pragma unroll
        for (int r = 0; r < 4; ++r) {
            int row = n0 + rbase + r;
            if (row < NN)
                out[(size_t)row * DO + j * 16 + arow] = acc[j][r] + bd;
        }
    }
}

extern "C" void kernel_launch(void* const* d_in, const int* in_sizes, int n_in,
                              void* d_out, int out_size, void* d_ws, size_t ws_size,
                              hipStream_t stream)
{
    const float* n_embed   = (const float*)d_in[0];
    const float* e_embed   = (const float*)d_in[1];
    const int*   senders   = (const int*)d_in[2];
    const int*   receivers = (const int*)d_in[3];
    const float* W1        = (const float*)d_in[4];
    const float* b1        = (const float*)d_in[5];
    const float* W2        = (const float*)d_in[6];
    const float* b2        = (const float*)d_in[7];
    float* out = (float*)d_out;

    unsigned short* Ps   = (unsigned short*)d_ws;             // [NN][192] bf16 (lane-packed)
    unsigned short* Pr   = Ps + (size_t)NN * DH;              // [NN][192] bf16 (lane-packed)
    float*          Hbar = (float*)(Pr + (size_t)NN * DH);    // [NN][192] f32
    int*            row_start = (int*)(Hbar + (size_t)NN * DH);  // [NN+1]

    const int prep_blocks = (PREP_ITEMS + 255) / 256;         // 3140
    prep_proj<<<NPROJ + prep_blocks, 256, 0, stream>>>(
        n_embed, W1, W2, b1, senders, Ps, Hbar, row_start);
    edge_reduce<<<E_TOT / EB, 256, 0, stream>>>(
        e_embed, senders, receivers, Ps, Pr, Hbar);
    node_out<<<(NN + 63) / 64, 256, 0, stream>>>(Hbar, row_start, b2, out);
}